// Round 4
// baseline (187.652 us; speedup 1.0000x reference)
//
#include <hip/hip_runtime.h>
#include <hip/hip_cooperative_groups.h>

#define DIM 8192
#define NLAYERS 8
#define NB 256                    // blocks (1 per CU guaranteed: 64 KB LDS)
#define NT 512                    // threads per block (8 waves)
#define ROWS_PB (DIM / NB)        // 32 rows per block in the quad pass
#define PRIME_ROW0 2048           // rows [2048, 8192) primed into L3 = 192 MB

namespace cg = cooperative_groups;

// swizzle: all LDS round patterns become even 4-way (b64 minimum) [GF(2)-verified]
__device__ __forceinline__ int swz(int i) { return i ^ ((i >> 4) & 15); }

__global__ __launch_bounds__(NT, 2) void fused_kernel(const float* __restrict__ params,
                                                      const float* __restrict__ O,
                                                      float* __restrict__ R,
                                                      float* __restrict__ M,
                                                      float* __restrict__ partials,
                                                      float* __restrict__ out) {
    __shared__ float2 buf[DIM];       // 64 KiB, single buffer
    __shared__ float wsum[8];
    const int t   = threadIdx.x;
    const int bid = blockIdx.x;
    cg::grid_group grid = cg::this_grid();

    // ====================== PHASE 1 ======================
    if (bid == 0) {
        // ---- statevector sim (identical math to the verified round-3 kernel,
        //      single-buffer: barrier before write AND before read) ----
        float2 a[16];
#pragma unroll
        for (int l = 0; l < 16; ++l) a[l] = make_float2(0.f, 0.f);
        if (t == 0) a[0].x = 1.f;

        for (int layer = 0; layer < NLAYERS; ++layer) {
            const float* __restrict__ prx = params + layer * 26;
            const float* __restrict__ prz = prx + 13;

            float cb[13], sb[13];
#pragma unroll
            for (int p = 0; p < 13; ++p) __sincosf(0.5f * prx[12 - p], &sb[p], &cb[p]);

            // RX group 0: i-bits 0..3 (local)
#pragma unroll
            for (int k = 0; k < 4; ++k) {
                const float c = cb[k], s = sb[k];
#pragma unroll
                for (int l0 = 0; l0 < 16; ++l0) {
                    if (!(l0 & (1 << k))) {
                        const int l1 = l0 | (1 << k);
                        const float2 a0 = a[l0], a1 = a[l1];
                        a[l0] = make_float2(fmaf(c, a0.x, s * a1.y), fmaf(c, a0.y, -s * a1.x));
                        a[l1] = make_float2(fmaf(c, a1.x, s * a0.y), fmaf(c, a1.y, -s * a0.x));
                    }
                }
            }

            // R1: canonical -> layout A
            __syncthreads();
#pragma unroll
            for (int l = 0; l < 16; ++l) buf[swz((t << 4) | l)] = a[l];
            __syncthreads();
#pragma unroll
            for (int l = 0; l < 16; ++l) a[l] = buf[swz((t & 15) | (l << 4) | ((t >> 4) << 8))];

            // RX group 1: i-bits 4..7
#pragma unroll
            for (int k = 0; k < 4; ++k) {
                const float c = cb[4 + k], s = sb[4 + k];
#pragma unroll
                for (int l0 = 0; l0 < 16; ++l0) {
                    if (!(l0 & (1 << k))) {
                        const int l1 = l0 | (1 << k);
                        const float2 a0 = a[l0], a1 = a[l1];
                        a[l0] = make_float2(fmaf(c, a0.x, s * a1.y), fmaf(c, a0.y, -s * a1.x));
                        a[l1] = make_float2(fmaf(c, a1.x, s * a0.y), fmaf(c, a1.y, -s * a0.x));
                    }
                }
            }

            // R2: layout A -> layout B
            __syncthreads();
#pragma unroll
            for (int l = 0; l < 16; ++l) buf[swz((t & 15) | (l << 4) | ((t >> 4) << 8))] = a[l];
            __syncthreads();
#pragma unroll
            for (int l = 0; l < 16; ++l)
                a[l] = buf[swz(((t >> 1) & 255) | (l << 8) | ((t & 1) << 12))];

            // RX group 2: i-bits 8..11
#pragma unroll
            for (int k = 0; k < 4; ++k) {
                const float c = cb[8 + k], s = sb[8 + k];
#pragma unroll
                for (int l0 = 0; l0 < 16; ++l0) {
                    if (!(l0 & (1 << k))) {
                        const int l1 = l0 | (1 << k);
                        const float2 a0 = a[l0], a1 = a[l1];
                        a[l0] = make_float2(fmaf(c, a0.x, s * a1.y), fmaf(c, a0.y, -s * a1.x));
                        a[l1] = make_float2(fmaf(c, a1.x, s * a0.y), fmaf(c, a1.y, -s * a0.x));
                    }
                }
            }

            // RX on bit 12: lane bit 0 via shfl_xor
            {
                const float c = cb[12], s = sb[12];
#pragma unroll
                for (int l = 0; l < 16; ++l) {
                    const float ox = __shfl_xor(a[l].x, 1);
                    const float oy = __shfl_xor(a[l].y, 1);
                    a[l] = make_float2(fmaf(c, a[l].x, s * oy), fmaf(c, a[l].y, -s * ox));
                }
            }

            // RZ diagonal (layout B)
            float hz[13];
#pragma unroll
            for (int p = 0; p < 13; ++p) hz[p] = 0.5f * prz[12 - p];
            float phiT = 0.f;
#pragma unroll
            for (int p = 0; p < 8; ++p) phiT += (((t >> 1) >> p) & 1) ? hz[p] : -hz[p];
            phiT += (t & 1) ? hz[12] : -hz[12];
#pragma unroll
            for (int l = 0; l < 16; ++l) {
                float phi = phiT;
                phi += (l & 1) ? hz[8]  : -hz[8];
                phi += (l & 2) ? hz[9]  : -hz[9];
                phi += (l & 4) ? hz[10] : -hz[10];
                phi += (l & 8) ? hz[11] : -hz[11];
                float sp, cp;
                __sincosf(phi, &sp, &cp);
                a[l] = make_float2(a[l].x * cp - a[l].y * sp, a[l].x * sp + a[l].y * cp);
            }

            // R3: CNOT round, layout B -> canonical (inverse suffix-parity gather)
            __syncthreads();
#pragma unroll
            for (int l = 0; l < 16; ++l)
                buf[swz(((t >> 1) & 255) | (l << 8) | ((t & 1) << 12))] = a[l];
            __syncthreads();
#pragma unroll
            for (int l = 0; l < 16; ++l) {
                const int c0 = (t << 4) | l;
                a[l] = buf[swz(c0 ^ (c0 >> 1))];
            }
        }

        // write r, m (canonical, contiguous float4)
#pragma unroll
        for (int g = 0; g < 4; ++g) {
            const float4 rv = make_float4(a[4*g].x, a[4*g+1].x, a[4*g+2].x, a[4*g+3].x);
            const float4 mv = make_float4(a[4*g].y, a[4*g+1].y, a[4*g+2].y, a[4*g+3].y);
            ((float4*)R)[(t << 2) + g] = rv;
            ((float4*)M)[(t << 2) + g] = mv;
        }
        __threadfence();   // device-scope: make R/M visible across XCDs
    } else {
        // ---- L3 prime: stream rows [PRIME_ROW0, DIM) of O, 192 MB ----
        const float4* __restrict__ O4 = (const float4*)O;
        const int Q    = (NB - 1) * NT;                       // 130560 prime threads
        const int b4   = (PRIME_ROW0 * DIM) / 4;              // 4194304
        const int e4   = (DIM * DIM) / 4;                     // 16777216
        const int q    = (bid - 1) * NT + t;
        float dummy = 0.f;
        for (int k = 0; k < 97; ++k) {
            const int idx = b4 + q + k * Q;
            if (idx < e4) {
                const float4 v = O4[idx];
                dummy += v.x + v.y + v.z + v.w;
            }
        }
        asm volatile("" :: "v"(dummy));   // keep loads live (no DCE)
    }

    grid.sync();

    // ====================== PHASE 2: quadratic form ======================
    {
        const float4* __restrict__ R4 = (const float4*)R;
        const float4* __restrict__ M4 = (const float4*)M;
        float4 rj[4], mj[4];
#pragma unroll
        for (int it = 0; it < 4; ++it) { rj[it] = R4[t + it * NT]; mj[it] = M4[t + it * NT]; }

        float acc = 0.f;
#pragma unroll 1
        for (int r = 0; r < ROWS_PB; ++r) {
            const int i = bid * ROWS_PB + r;
            const float ri = R[i];
            const float mi = M[i];
            const float4* __restrict__ Or = (const float4*)(O + (size_t)i * DIM);
            float sR = 0.f, sM = 0.f;
#pragma unroll
            for (int it = 0; it < 4; ++it) {
                const float4 o = Or[t + it * NT];
                sR = fmaf(o.x, rj[it].x, sR); sR = fmaf(o.y, rj[it].y, sR);
                sR = fmaf(o.z, rj[it].z, sR); sR = fmaf(o.w, rj[it].w, sR);
                sM = fmaf(o.x, mj[it].x, sM); sM = fmaf(o.y, mj[it].y, sM);
                sM = fmaf(o.z, mj[it].z, sM); sM = fmaf(o.w, mj[it].w, sM);
            }
            acc = fmaf(ri, sR, acc);
            acc = fmaf(mi, sM, acc);
        }

        // block reduction (8 waves)
#pragma unroll
        for (int off = 32; off > 0; off >>= 1) acc += __shfl_down(acc, off);
        __syncthreads();                 // buf/wsum reuse safety
        if ((t & 63) == 0) wsum[t >> 6] = acc;
        __syncthreads();
        if (t == 0) {
            float s = 0.f;
#pragma unroll
            for (int k = 0; k < 8; ++k) s += wsum[k];
            partials[bid] = s;
        }
        __threadfence();
    }

    grid.sync();

    // ====================== PHASE 3: final reduce (block 0) ======================
    if (bid == 0) {
        float v = (t < NB) ? partials[t] : 0.f;
#pragma unroll
        for (int off = 32; off > 0; off >>= 1) v += __shfl_down(v, off);
        __syncthreads();
        if ((t & 63) == 0) wsum[t >> 6] = v;
        __syncthreads();
        if (t == 0) out[0] = wsum[0] + wsum[1] + wsum[2] + wsum[3];  // t<256 -> waves 0..3
    }
}

extern "C" void kernel_launch(void* const* d_in, const int* in_sizes, int n_in,
                              void* d_out, int out_size, void* d_ws, size_t ws_size,
                              hipStream_t stream) {
    const float* params = (const float*)d_in[0];   // 208 fp32
    const float* O      = (const float*)d_in[1];   // 8192*8192 fp32
    float* out = (float*)d_out;

    float* R        = (float*)d_ws;
    float* M        = R + DIM;
    float* partials = M + DIM;

    void* args[] = { (void*)&params, (void*)&O, (void*)&R, (void*)&M,
                     (void*)&partials, (void*)&out };
    hipLaunchCooperativeKernel((const void*)fused_kernel, dim3(NB), dim3(NT),
                               args, 0, stream);
}

// Round 5
// 83.397 us; speedup vs baseline: 2.2501x; 2.2501x over previous
//
#include <hip/hip_runtime.h>

#define DIM 8192
#define NLAYERS 8
#define SIMT 512        // sim/prime threads per block
#define NB_A 256        // kernel A blocks: block 0 = sim, 1..255 = L3 prime
#define PRIME_ROW0 2048 // rows [2048,8192) primed = 192 MB (< 256 MB L3)
#define QFB 2048
#define QFT 256
#define ROWS_PER_BLOCK 4

typedef float floatx4 __attribute__((ext_vector_type(4)));

// swizzle: all LDS round patterns become even 4-way (b64 minimum) [GF(2)-verified]
__device__ __forceinline__ int swz(int i) { return i ^ ((i >> 4) & 15); }

// ---------------------------------------------------------------------------
// Kernel A: block 0 = statevector sim (round-3 verified math, ping-pong LDS);
//           blocks 1..255 = stream rows [2048,8192) of O to prime L3.
// No inter-block communication: the kernel boundary is the sync.
// ---------------------------------------------------------------------------
__global__ __launch_bounds__(SIMT) void simprime_kernel(const float* __restrict__ params,
                                                        const float* __restrict__ O,
                                                        float* __restrict__ outR,
                                                        float* __restrict__ outM) {
    __shared__ float2 buf[2][DIM];   // 128 KiB ping-pong (only block 0 uses it)
    const int t = threadIdx.x;

    if (blockIdx.x != 0) {
        // ---- L3 prime: 192 MB, coalesced grid-stride float4 sweep ----
        const floatx4* __restrict__ O4 = (const floatx4*)O;
        const int Q  = (NB_A - 1) * SIMT;          // 130560 prime threads
        const int b4 = (PRIME_ROW0 * DIM) / 4;     // 4194304
        const int e4 = (DIM * DIM) / 4;            // 16777216
        const int q  = ((int)blockIdx.x - 1) * SIMT + t;
        float dummy = 0.f;
        for (int k = 0; k < 97; ++k) {
            const int idx = b4 + q + k * Q;
            if (idx < e4) {
                const floatx4 v = O4[idx];
                dummy += v.x + v.y + v.z + v.w;
            }
        }
        asm volatile("" :: "v"(dummy));   // keep loads live (no DCE)
        return;
    }

    // ---- statevector sim, qubit q <-> bit p = 12-q; layouts C/A/B cycle ----
    float2 a[16];
#pragma unroll
    for (int l = 0; l < 16; ++l) a[l] = make_float2(0.f, 0.f);
    if (t == 0) a[0].x = 1.f;

    int pp = 0;  // ping-pong parity

    for (int layer = 0; layer < NLAYERS; ++layer) {
        const float* __restrict__ prx = params + layer * 26;
        const float* __restrict__ prz = prx + 13;

        float cb[13], sb[13];
#pragma unroll
        for (int p = 0; p < 13; ++p) __sincosf(0.5f * prx[12 - p], &sb[p], &cb[p]);

        // RX group 0: i-bits 0..3 (register-local)
#pragma unroll
        for (int k = 0; k < 4; ++k) {
            const float c = cb[k], s = sb[k];
#pragma unroll
            for (int l0 = 0; l0 < 16; ++l0) {
                if (!(l0 & (1 << k))) {
                    const int l1 = l0 | (1 << k);
                    const float2 a0 = a[l0], a1 = a[l1];
                    a[l0] = make_float2(fmaf(c, a0.x, s * a1.y), fmaf(c, a0.y, -s * a1.x));
                    a[l1] = make_float2(fmaf(c, a1.x, s * a0.y), fmaf(c, a1.y, -s * a0.x));
                }
            }
        }

        // R1: canonical -> layout A
        {
            float2* __restrict__ B = buf[pp]; pp ^= 1;
#pragma unroll
            for (int l = 0; l < 16; ++l) B[swz((t << 4) | l)] = a[l];
            __syncthreads();
#pragma unroll
            for (int l = 0; l < 16; ++l) a[l] = B[swz((t & 15) | (l << 4) | ((t >> 4) << 8))];
        }

        // RX group 1: i-bits 4..7
#pragma unroll
        for (int k = 0; k < 4; ++k) {
            const float c = cb[4 + k], s = sb[4 + k];
#pragma unroll
            for (int l0 = 0; l0 < 16; ++l0) {
                if (!(l0 & (1 << k))) {
                    const int l1 = l0 | (1 << k);
                    const float2 a0 = a[l0], a1 = a[l1];
                    a[l0] = make_float2(fmaf(c, a0.x, s * a1.y), fmaf(c, a0.y, -s * a1.x));
                    a[l1] = make_float2(fmaf(c, a1.x, s * a0.y), fmaf(c, a1.y, -s * a0.x));
                }
            }
        }

        // R2: layout A -> layout B
        {
            float2* __restrict__ B = buf[pp]; pp ^= 1;
#pragma unroll
            for (int l = 0; l < 16; ++l) B[swz((t & 15) | (l << 4) | ((t >> 4) << 8))] = a[l];
            __syncthreads();
#pragma unroll
            for (int l = 0; l < 16; ++l)
                a[l] = B[swz(((t >> 1) & 255) | (l << 8) | ((t & 1) << 12))];
        }

        // RX group 2: i-bits 8..11
#pragma unroll
        for (int k = 0; k < 4; ++k) {
            const float c = cb[8 + k], s = sb[8 + k];
#pragma unroll
            for (int l0 = 0; l0 < 16; ++l0) {
                if (!(l0 & (1 << k))) {
                    const int l1 = l0 | (1 << k);
                    const float2 a0 = a[l0], a1 = a[l1];
                    a[l0] = make_float2(fmaf(c, a0.x, s * a1.y), fmaf(c, a0.y, -s * a1.x));
                    a[l1] = make_float2(fmaf(c, a1.x, s * a0.y), fmaf(c, a1.y, -s * a0.x));
                }
            }
        }

        // RX on bit 12: lane bit 0 via shfl_xor
        {
            const float c = cb[12], s = sb[12];
#pragma unroll
            for (int l = 0; l < 16; ++l) {
                const float ox = __shfl_xor(a[l].x, 1);
                const float oy = __shfl_xor(a[l].y, 1);
                a[l] = make_float2(fmaf(c, a[l].x, s * oy), fmaf(c, a[l].y, -s * ox));
            }
        }

        // RZ diagonal (layout B)
        float hz[13];
#pragma unroll
        for (int p = 0; p < 13; ++p) hz[p] = 0.5f * prz[12 - p];
        float phiT = 0.f;
#pragma unroll
        for (int p = 0; p < 8; ++p) phiT += (((t >> 1) >> p) & 1) ? hz[p] : -hz[p];
        phiT += (t & 1) ? hz[12] : -hz[12];
#pragma unroll
        for (int l = 0; l < 16; ++l) {
            float phi = phiT;
            phi += (l & 1) ? hz[8]  : -hz[8];
            phi += (l & 2) ? hz[9]  : -hz[9];
            phi += (l & 4) ? hz[10] : -hz[10];
            phi += (l & 8) ? hz[11] : -hz[11];
            float sp, cp;
            __sincosf(phi, &sp, &cp);
            a[l] = make_float2(a[l].x * cp - a[l].y * sp, a[l].x * sp + a[l].y * cp);
        }

        // R3: CNOT round, layout B -> canonical (inverse suffix-parity gather)
        {
            float2* __restrict__ B = buf[pp]; pp ^= 1;
#pragma unroll
            for (int l = 0; l < 16; ++l)
                B[swz(((t >> 1) & 255) | (l << 8) | ((t & 1) << 12))] = a[l];
            __syncthreads();
#pragma unroll
            for (int l = 0; l < 16; ++l) {
                const int c0 = (t << 4) | l;
                a[l] = B[swz(c0 ^ (c0 >> 1))];
            }
        }
    }

    // write r, m (canonical, contiguous float4)
#pragma unroll
    for (int g = 0; g < 4; ++g) {
        const float4 rv = make_float4(a[4*g].x, a[4*g+1].x, a[4*g+2].x, a[4*g+3].x);
        const float4 mv = make_float4(a[4*g].y, a[4*g+1].y, a[4*g+2].y, a[4*g+3].y);
        ((float4*)outR)[(t << 2) + g] = rv;
        ((float4*)outM)[(t << 2) + g] = mv;
    }
}

// ---------------------------------------------------------------------------
// Kernel B: loss partials = r^T O r + m^T O m.
// Cold rows (< PRIME_ROW0): nontemporal loads (don't evict primed L3 lines).
// Primed rows: cached loads -> L3 hits.
// ---------------------------------------------------------------------------
__global__ __launch_bounds__(QFT) void quad_kernel(const float* __restrict__ O,
                                                   const float* __restrict__ R,
                                                   const float* __restrict__ M,
                                                   float* __restrict__ partials) {
    const int bi = blockIdx.x;
    const int t  = threadIdx.x;
    const float4* __restrict__ R4 = (const float4*)R;
    const float4* __restrict__ M4 = (const float4*)M;

    float acc = 0.f;
#pragma unroll
    for (int rr = 0; rr < ROWS_PER_BLOCK; ++rr) {
        const int i = bi * ROWS_PER_BLOCK + rr;
        const float ri = R[i];
        const float mi = M[i];
        const floatx4* __restrict__ Or = (const floatx4*)(O + (size_t)i * DIM);
        if (i < PRIME_ROW0) {
#pragma unroll
            for (int it = 0; it < DIM / 4 / QFT; ++it) {
                const int j4 = t + it * QFT;
                const floatx4 o = __builtin_nontemporal_load(&Or[j4]);
                const float4 rj = R4[j4];
                const float4 mj = M4[j4];
                acc = fmaf(o.x, fmaf(ri, rj.x, mi * mj.x), acc);
                acc = fmaf(o.y, fmaf(ri, rj.y, mi * mj.y), acc);
                acc = fmaf(o.z, fmaf(ri, rj.z, mi * mj.z), acc);
                acc = fmaf(o.w, fmaf(ri, rj.w, mi * mj.w), acc);
            }
        } else {
#pragma unroll
            for (int it = 0; it < DIM / 4 / QFT; ++it) {
                const int j4 = t + it * QFT;
                const floatx4 o = Or[j4];
                const float4 rj = R4[j4];
                const float4 mj = M4[j4];
                acc = fmaf(o.x, fmaf(ri, rj.x, mi * mj.x), acc);
                acc = fmaf(o.y, fmaf(ri, rj.y, mi * mj.y), acc);
                acc = fmaf(o.z, fmaf(ri, rj.z, mi * mj.z), acc);
                acc = fmaf(o.w, fmaf(ri, rj.w, mi * mj.w), acc);
            }
        }
    }

#pragma unroll
    for (int off = 32; off > 0; off >>= 1) acc += __shfl_down(acc, off);
    __shared__ float wsum[QFT / 64];
    const int lane = t & 63, w = t >> 6;
    if (lane == 0) wsum[w] = acc;
    __syncthreads();
    if (t == 0) {
        float s = 0.f;
#pragma unroll
        for (int k = 0; k < QFT / 64; ++k) s += wsum[k];
        partials[bi] = s;
    }
}

__global__ __launch_bounds__(256) void reduce_kernel(const float* __restrict__ partials,
                                                     float* __restrict__ out) {
    const int t = threadIdx.x;
    float acc = 0.f;
#pragma unroll
    for (int k = 0; k < QFB / 256; ++k) acc += partials[t + k * 256];
#pragma unroll
    for (int off = 32; off > 0; off >>= 1) acc += __shfl_down(acc, off);
    __shared__ float wsum[4];
    const int lane = t & 63, w = t >> 6;
    if (lane == 0) wsum[w] = acc;
    __syncthreads();
    if (t == 0) out[0] = wsum[0] + wsum[1] + wsum[2] + wsum[3];
}

extern "C" void kernel_launch(void* const* d_in, const int* in_sizes, int n_in,
                              void* d_out, int out_size, void* d_ws, size_t ws_size,
                              hipStream_t stream) {
    const float* params = (const float*)d_in[0];   // 208 fp32
    const float* O      = (const float*)d_in[1];   // 8192*8192 fp32
    float* out = (float*)d_out;

    float* R        = (float*)d_ws;
    float* M        = R + DIM;
    float* partials = M + DIM;

    simprime_kernel<<<NB_A, SIMT, 0, stream>>>(params, O, R, M);
    quad_kernel<<<QFB, QFT, 0, stream>>>(O, R, M, partials);
    reduce_kernel<<<1, 256, 0, stream>>>(partials, out);
}